// Round 3
// baseline (1545.175 us; speedup 1.0000x reference)
//
#include <hip/hip_runtime.h>

#define B 16
#define N 8192
#define S1 512
#define S2 128
#define K 64

typedef float v2f __attribute__((ext_vector_type(2)));

// ---------------------------------------------------------------------------
// DPP helper: cross-lane reduction on the VALU (no LDS pipe).
// ---------------------------------------------------------------------------
template<int CTRL>
__device__ __forceinline__ unsigned dpp_u32(unsigned v) {
  return (unsigned)__builtin_amdgcn_update_dpp((int)v, (int)v, CTRL, 0xF, 0xF, false);
}

// u64 max reduction step: 2 DPP movs + u64 compare + 2 cndmask.
template<int CTRL>
__device__ __forceinline__ void red64(unsigned long long& k) {
  unsigned hi = (unsigned)(k >> 32), lo = (unsigned)k;
  unsigned ohi = dpp_u32<CTRL>(hi);
  unsigned olo = dpp_u32<CTRL>(lo);
  unsigned long long o = ((unsigned long long)ohi << 32) | olo;
  if (o > k) k = o;
}

// ---------------------------------------------------------------------------
// Farthest point sampling body. ROUND-10 (R9 post-mortem): fps1 at 485us with
// VGPR_Count=28 (state squeezed out AGAIN: __launch_bounds__(NT,1) only sets a
// MIN waves/EU; allocator targeted the 8-wave tier and re-loads all 24 coord
// floats/thread/iter) and VALUBusy 6.26% == 100% x 16/256 CUs: the active CUs'
// VALU issue is saturated -> pure instruction-count-bound. This round:
//  * VGPR pin via non-template wrappers with amdgpu_waves_per_eu(max clamped)
//    (the R8 lesson: clamping MAX is what stops the squeeze). State resident.
//  * packed fp32: distance core on v2f (ext_vector) pairs -> backend emits
//    v_pk_sub/v_pk_fma (VOP3P, 2 f32/op): 6 dist ops/pt -> 3.
//  * no nidx[] array: 3-bit winner code (inline consts), p = t + code*NT
//    reconstructed once per iter.
// Tie semantics preserved everywhere (= jnp.argmax first occurrence = min idx):
// in-thread strict > over ascending codes; cross-half tie -> smaller code;
// cross-lane/wave via u64 key (dist_bits<<32)|~idx, max ~idx == min idx.
// Stage-2: lane63 ds atomicMax(u64) on one LDS cell; 3-cell rotation cleared
// one iter ahead keeps it race-free with a single barrier per iteration.
// Requires n == PT * NT exactly; npoint <= MAXP.
// ---------------------------------------------------------------------------
template<int NT, int PT, int MAXP>
__device__ __forceinline__ void fps_body(
    const float* __restrict__ pts, float* __restrict__ out_xyz,
    float* __restrict__ out2, int out2_stride, int n, int npoint) {
  const int b = blockIdx.x;
  const int t = threadIdx.x;
  const int lane = t & 63;
  const float* base = pts + (size_t)b * n * 3;
  __shared__ unsigned long long cell[3];
  __shared__ float s_out[MAXP * 3];
  if (t == 0) { cell[0] = 0ull; cell[1] = 0ull; cell[2] = 0ull; }
  // first sample is index 0
  float cx = base[0], cy = base[1], cz = base[2];

  if constexpr (PT >= 2) {
    constexpr int PH = PT / 2;
    v2f px[PH], py[PH], pz[PH], mind[PH];
#pragma unroll
    for (int j = 0; j < PH; j++) {
      int p0 = t + (2 * j) * NT, p1 = t + (2 * j + 1) * NT;
      px[j] = (v2f){base[p0 * 3 + 0], base[p1 * 3 + 0]};
      py[j] = (v2f){base[p0 * 3 + 1], base[p1 * 3 + 1]};
      pz[j] = (v2f){base[p0 * 3 + 2], base[p1 * 3 + 2]};
      mind[j] = (v2f){1e10f, 1e10f};  // matches reference init 1e10
    }
    __syncthreads();
    for (int it = 0; it < npoint; it++) {
      if (t == 0) {
        s_out[it * 3 + 0] = cx; s_out[it * 3 + 1] = cy; s_out[it * 3 + 2] = cz;
      }
      const v2f ccx = {cx, cx}, ccy = {cy, cy}, ccz = {cz, cz};
      v2f bv = {-1.0f, -1.0f};
      int bcx = 0, bcy = 1;  // winner codes per half (x: even, y: odd)
#pragma unroll
      for (int j = 0; j < PH; j++) {
        v2f dx = px[j] - ccx;
        v2f dy = py[j] - ccy;
        v2f dz = pz[j] - ccz;
        v2f d = dx * dx;                          // v_pk_mul
        d = __builtin_elementwise_fma(dy, dy, d); // v_pk_fma
        d = __builtin_elementwise_fma(dz, dz, d); // v_pk_fma
        v2f md = __builtin_elementwise_min(mind[j], d);
        mind[j] = md;
        if (md.x > bv.x) { bv.x = md.x; bcx = 2 * j; }
        if (md.y > bv.y) { bv.y = md.y; bcy = 2 * j + 1; }
      }
      // combine halves; exact-tie -> smaller code (= smaller global index)
      float bvs = bv.x;
      int bc = bcx;
      if (bv.y > bv.x || (bv.y == bv.x && bcy < bcx)) { bvs = bv.y; bc = bcy; }
      unsigned long long k =
          ((unsigned long long)__float_as_uint(bvs) << 32) | (~(unsigned)(t + bc * NT));
      red64<0x111>(k);  // row_shr:1
      red64<0x112>(k);  // row_shr:2
      red64<0x114>(k);  // row_shr:4
      red64<0x118>(k);  // row_shr:8
      red64<0x142>(k);  // row_bcast:15
      red64<0x143>(k);  // row_bcast:31  -> lane 63 has wave winner
      if (lane == 63) atomicMax(&cell[it % 3], k);
      if (t == 0) cell[(it + 1) % 3] = 0ull;  // prep next iter's cell
      __syncthreads();
      unsigned long long wk = cell[it % 3];
      int ui = __builtin_amdgcn_readfirstlane((int)(~(unsigned)wk));
      const float* q = base + (size_t)ui * 3;  // uniform address -> scalar load
      cx = q[0]; cy = q[1]; cz = q[2];
    }
  } else {
    // scalar path (PT == 1), used by the small second-stage FPS
    float px = base[t * 3 + 0], py = base[t * 3 + 1], pz = base[t * 3 + 2];
    float mind = 1e10f;
    __syncthreads();
    for (int it = 0; it < npoint; it++) {
      if (t == 0) {
        s_out[it * 3 + 0] = cx; s_out[it * 3 + 1] = cy; s_out[it * 3 + 2] = cz;
      }
      float dx = px - cx, dy = py - cy, dz = pz - cz;
      float d = dx * dx;
      d = fmaf(dy, dy, d);
      d = fmaf(dz, dz, d);
      mind = fminf(mind, d);
      unsigned long long k =
          ((unsigned long long)__float_as_uint(mind) << 32) | (~(unsigned)t);
      red64<0x111>(k);
      red64<0x112>(k);
      red64<0x114>(k);
      red64<0x118>(k);
      red64<0x142>(k);
      red64<0x143>(k);
      if (lane == 63) atomicMax(&cell[it % 3], k);
      if (t == 0) cell[(it + 1) % 3] = 0ull;
      __syncthreads();
      unsigned long long wk = cell[it % 3];
      int ui = __builtin_amdgcn_readfirstlane((int)(~(unsigned)wk));
      const float* q = base + (size_t)ui * 3;
      cx = q[0]; cy = q[1]; cz = q[2];
    }
  }
  // epilogue: flush staged sample coords to global (coalesced)
  for (int e = t; e < npoint * 3; e += NT)
    out_xyz[(size_t)b * npoint * 3 + e] = s_out[e];
  if (out2) {
    for (int e = t; e < npoint; e += NT) {
      float* o2 = out2 + ((size_t)b * npoint + e) * out2_stride;
      o2[0] = s_out[e * 3 + 0];
      o2[1] = s_out[e * 3 + 1];
      o2[2] = s_out[e * 3 + 2];
    }
  }
}

// Wrappers pin the VGPR budget to the real occupancy (one block/CU):
// fps1: 1024 thr = 4 waves/SIMD -> waves_per_eu(4,4) -> 512-VGPR budget.
// fps2: 512 thr = 2 waves/SIMD -> waves_per_eu(2,2).
__global__ __launch_bounds__(1024) __attribute__((amdgpu_waves_per_eu(4, 4)))
void fps1_kernel(const float* __restrict__ pts, float* __restrict__ out_xyz,
                 float* __restrict__ out2, int out2_stride, int n, int npoint) {
  fps_body<1024, 8, 512>(pts, out_xyz, out2, out2_stride, n, npoint);
}

__global__ __launch_bounds__(512) __attribute__((amdgpu_waves_per_eu(2, 2)))
void fps2_kernel(const float* __restrict__ pts, float* __restrict__ out_xyz,
                 float* __restrict__ out2, int out2_stride, int n, int npoint) {
  fps_body<512, 1, 128>(pts, out_xyz, out2, out2_stride, n, npoint);
}

// ---------------------------------------------------------------------------
// Ball query: one wave per center; ballot-scan points in index order, emit
// first K in-radius indices; fill tail with first hit (or n-1 if none).
// ---------------------------------------------------------------------------
__global__ __launch_bounds__(256) void ballq_kernel(
    const float* __restrict__ pts, const float* __restrict__ ctr,
    int* __restrict__ idx, int n, int ns, int total, float r2) {
  int gid = blockIdx.x * blockDim.x + threadIdx.x;
  int wid = gid >> 6;
  int lane = threadIdx.x & 63;
  if (wid >= total) return;
  int b = wid / ns, s = wid - b * ns;
  const float* pb = pts + (size_t)b * n * 3;
  const float* c = ctr + ((size_t)b * ns + s) * 3;
  float cx = c[0], cy = c[1], cz = c[2];
  float sc = cx * cx + cy * cy + cz * cz;
  int* out = idx + ((size_t)b * ns + s) * K;
  int cnt = 0, first = n - 1;
  for (int base = 0; base < n && cnt < K; base += 64) {
    int p = base + lane;
    float x = pb[p * 3 + 0], y = pb[p * 3 + 1], z = pb[p * 3 + 2];
    float sp = x * x + y * y + z * z;
    float dot = cx * x + cy * y + cz * z;
    float d2 = sc + sp - 2.0f * dot;
    bool inr = d2 < r2;
    unsigned long long m = __ballot(inr);
    if (cnt == 0 && m != 0ull) first = base + __ffsll((long long)m) - 1;
    int pre = (int)__popcll(m & ((1ull << lane) - 1ull));
    if (inr && (cnt + pre) < K) out[cnt + pre] = p;
    cnt += (int)__popcll(m);
  }
  if (cnt > K) cnt = K;
  if (lane >= cnt) out[lane] = first;
}

// ---------------------------------------------------------------------------
// SA1 grouped MLP: per group (b,s): gather 64 local coords, h = relu(W1a*g+b),
// out[o] = relu(max_k (W1b[o].h[k] + b)). h staged in LDS; W1b row in regs;
// all LDS reads are wave-uniform broadcasts (conflict-free).
// ---------------------------------------------------------------------------
__global__ __launch_bounds__(256) void sa1_kernel(
    const float* __restrict__ xyz, const int* __restrict__ idx,
    const float* __restrict__ ctr, const float* __restrict__ W1a,
    const float* __restrict__ b1a, const float* __restrict__ W1b,
    const float* __restrict__ b1b, float* __restrict__ feat) {
  __shared__ float s_l[K][3];
  __shared__ float s_h[K][64];
  __shared__ float s_red[128];
  int blk = blockIdx.x;
  int b = blk >> 9, s = blk & 511;
  int tid = threadIdx.x;
  const int* gi = idx + ((size_t)b * S1 + s) * K;
  const float* c = ctr + ((size_t)b * S1 + s) * 3;
  float cx = c[0], cy = c[1], cz = c[2];
  if (tid < K) {
    int p = gi[tid];
    const float* q = xyz + ((size_t)b * N + p) * 3;
    s_l[tid][0] = q[0] - cx;
    s_l[tid][1] = q[1] - cy;
    s_l[tid][2] = q[2] - cz;
  }
  __syncthreads();
  for (int e = tid; e < K * 64; e += 256) {
    int k = e >> 6, o = e & 63;
    float v = b1a[o] + W1a[o * 3 + 0] * s_l[k][0] + W1a[o * 3 + 1] * s_l[k][1] +
              W1a[o * 3 + 2] * s_l[k][2];
    s_h[k][o] = fmaxf(v, 0.f);
  }
  __syncthreads();
  int o = tid & 127, half = tid >> 7;
  float w[64];
  const float4* wp = (const float4*)(W1b + o * 64);  // 256B-aligned rows
#pragma unroll
  for (int c4 = 0; c4 < 16; c4++) {
    float4 t4 = wp[c4];
    w[c4 * 4 + 0] = t4.x; w[c4 * 4 + 1] = t4.y;
    w[c4 * 4 + 2] = t4.z; w[c4 * 4 + 3] = t4.w;
  }
  float bias = b1b[o];
  float m = -1e30f;
  int k0 = half * 32;
  for (int k = k0; k < k0 + 32; k++) {
    float acc = bias;
    const float4* hp = (const float4*)(&s_h[k][0]);
#pragma unroll
    for (int c4 = 0; c4 < 16; c4++) {
      float4 h = hp[c4];  // broadcast across the wave
      acc = fmaf(h.x, w[c4 * 4 + 0], acc);
      acc = fmaf(h.y, w[c4 * 4 + 1], acc);
      acc = fmaf(h.z, w[c4 * 4 + 2], acc);
      acc = fmaf(h.w, w[c4 * 4 + 3], acc);
    }
    m = fmaxf(m, acc);
  }
  if (half == 1) s_red[o] = m;
  __syncthreads();
  if (half == 0) {
    m = fmaxf(m, s_red[o]);
    feat[((size_t)b * S1 + s) * 128 + o] = fmaxf(m, 0.f);  // relu(max) == max(relu)
  }
}

// ---------------------------------------------------------------------------
// SA2 grouped MLP: group input = [local xyz (3) | gathered feat1 (128)] = 131,
// 131 -> 128 (relu) -> 256 (relu) -> max over 64 samples. Output written
// directly into the concat buffer in3[b][s][3..258]; in3[..][0..2] = xyz2
// (written by fps2_kernel's out2 path).
// ---------------------------------------------------------------------------
__global__ __launch_bounds__(256) void sa2_kernel(
    const float* __restrict__ xyz1, const float* __restrict__ feat1,
    const int* __restrict__ idx, const float* __restrict__ ctr,
    const float* __restrict__ W2a, const float* __restrict__ b2a,
    const float* __restrict__ W2b, const float* __restrict__ b2b,
    float* __restrict__ in3) {
  __shared__ int s_pi[K];
  __shared__ float s_g[K][132];  // 131 cols + pad; row = 528B (16B aligned)
  __shared__ float s_h[K][128];
  int blk = blockIdx.x;
  int b = blk >> 7, s = blk & 127;
  int tid = threadIdx.x;
  const int* gi = idx + ((size_t)b * S2 + s) * K;
  const float* c = ctr + ((size_t)b * S2 + s) * 3;
  float cx = c[0], cy = c[1], cz = c[2];
  if (tid < K) {
    int p = gi[tid];
    s_pi[tid] = p;
    const float* q = xyz1 + ((size_t)b * S1 + p) * 3;
    s_g[tid][0] = q[0] - cx;
    s_g[tid][1] = q[1] - cy;
    s_g[tid][2] = q[2] - cz;
  }
  __syncthreads();
  for (int e = tid; e < K * 128; e += 256) {
    int k = e >> 7, f = e & 127;
    s_g[k][3 + f] = feat1[((size_t)b * S1 + s_pi[k]) * 128 + f];
  }
  __syncthreads();
  // phase A: s_h[k][o] = relu(W2a[o] . g[k] + b2a[o]), o in [0,128), k split in halves
  {
    int o = tid & 127, half = tid >> 7, k0 = half * 32;
    const float* wr = W2a + o * 131;
    float acc[32];
    float bias = b2a[o];
#pragma unroll
    for (int j = 0; j < 32; j++) acc[j] = bias;
    for (int c4 = 0; c4 < 32; c4++) {
      float w0 = wr[c4 * 4 + 0], w1 = wr[c4 * 4 + 1];
      float w2 = wr[c4 * 4 + 2], w3 = wr[c4 * 4 + 3];
#pragma unroll
      for (int j = 0; j < 32; j++) {
        float4 g = *(const float4*)(&s_g[k0 + j][c4 * 4]);
        acc[j] = fmaf(g.x, w0, acc[j]);
        acc[j] = fmaf(g.y, w1, acc[j]);
        acc[j] = fmaf(g.z, w2, acc[j]);
        acc[j] = fmaf(g.w, w3, acc[j]);
      }
    }
    float w0 = wr[128], w1 = wr[129], w2 = wr[130];
#pragma unroll
    for (int j = 0; j < 32; j++) {
      acc[j] = fmaf(s_g[k0 + j][128], w0, acc[j]);
      acc[j] = fmaf(s_g[k0 + j][129], w1, acc[j]);
      acc[j] = fmaf(s_g[k0 + j][130], w2, acc[j]);
      s_h[k0 + j][o] = fmaxf(acc[j], 0.f);
    }
  }
  __syncthreads();
  // phase B: out[o] = relu(max_k (W2b[o] . h[k] + b2b[o])), o = tid in [0,256)
  {
    int o = tid;
    const float4* wp = (const float4*)(W2b + o * 128);  // 512B-aligned rows
    float bias = b2b[o];
    float acc[K];
#pragma unroll
    for (int k = 0; k < K; k++) acc[k] = bias;
    for (int c4 = 0; c4 < 32; c4++) {
      float4 w4 = wp[c4];
#pragma unroll
      for (int k = 0; k < K; k++) {
        float4 h = *(const float4*)(&s_h[k][c4 * 4]);  // broadcast
        acc[k] = fmaf(h.x, w4.x, acc[k]);
        acc[k] = fmaf(h.y, w4.y, acc[k]);
        acc[k] = fmaf(h.z, w4.z, acc[k]);
        acc[k] = fmaf(h.w, w4.w, acc[k]);
      }
    }
    float m = -1e30f;
#pragma unroll
    for (int k = 0; k < K; k++) m = fmaxf(m, acc[k]);
    in3[((size_t)b * S2 + s) * 259 + 3 + o] = fmaxf(m, 0.f);
  }
}

// ---------------------------------------------------------------------------
// Final MLP layer a: h3[b][s][o] = relu(W3a[o] . in3[b][s] + b3a[o]).
// ---------------------------------------------------------------------------
__global__ __launch_bounds__(256) void mlp3a_kernel(
    const float* __restrict__ in3, const float* __restrict__ W3a,
    const float* __restrict__ b3a, float* __restrict__ h3) {
  __shared__ float s_wt[64][65];
  __shared__ float s_a[64][64];
  int blk = blockIdx.x;
  int b = blk >> 4, r = blk & 15;
  int ot = r >> 1, sh = r & 1;
  int tid = threadIdx.x;
  int o = tid & 63, sq = tid >> 6;
  float acc[16];
  float bias = b3a[ot * 64 + o];
#pragma unroll
  for (int j = 0; j < 16; j++) acc[j] = bias;
  for (int ch = 0; ch < 5; ch++) {
    int cb = ch * 64;
    int len = (ch == 4) ? 3 : 64;
    for (int e = tid; e < 4096; e += 256) {
      int oo = e >> 6, cc = e & 63;
      if (cc < len) s_wt[cc][oo] = W3a[(size_t)(ot * 64 + oo) * 259 + cb + cc];
    }
    for (int e = tid; e < 4096; e += 256) {
      int ss = e >> 6, cc = e & 63;
      if (cc < len) s_a[ss][cc] = in3[((size_t)b * S2 + sh * 64 + ss) * 259 + cb + cc];
    }
    __syncthreads();
    for (int cc = 0; cc < len; cc++) {
      float wv = s_wt[cc][o];
#pragma unroll
      for (int j = 0; j < 16; j++)
        acc[j] = fmaf(wv, s_a[sq * 16 + j][cc], acc[j]);
    }
    __syncthreads();
  }
#pragma unroll
  for (int j = 0; j < 16; j++) {
    int s = sh * 64 + sq * 16 + j;
    h3[((size_t)b * S2 + s) * 512 + ot * 64 + o] = fmaxf(acc[j], 0.f);
  }
}

// ---------------------------------------------------------------------------
// Final MLP layer b + global max-pool over the 128 proposals:
// out[b][o] = relu(max_s (W3b[o] . h3[b][s] + b3b[o])).
// ---------------------------------------------------------------------------
__global__ __launch_bounds__(256) void mlp3b_kernel(
    const float* __restrict__ h3, const float* __restrict__ W3b,
    const float* __restrict__ b3b, float* __restrict__ out) {
  __shared__ float s_wt[64][65];
  __shared__ float s_h[128][64];
  __shared__ float s_red[4][64];
  int blk = blockIdx.x;
  int b = blk >> 4, ot = blk & 15;
  int tid = threadIdx.x;
  int o = tid & 63, sq = tid >> 6;
  float acc[32];
  float bias = b3b[ot * 64 + o];
#pragma unroll
  for (int j = 0; j < 32; j++) acc[j] = bias;
  for (int ch = 0; ch < 8; ch++) {
    int cb = ch * 64;
    for (int e = tid; e < 4096; e += 256) {
      int oo = e >> 6, cc = e & 63;
      s_wt[cc][oo] = W3b[(size_t)(ot * 64 + oo) * 512 + cb + cc];
    }
    for (int e = tid; e < 8192; e += 256) {
      int ss = e >> 6, cc = e & 63;
      s_h[ss][cc] = h3[((size_t)b * S2 + ss) * 512 + cb + cc];
    }
    __syncthreads();
    for (int c4 = 0; c4 < 16; c4++) {
      float w0 = s_wt[c4 * 4 + 0][o];
      float w1 = s_wt[c4 * 4 + 1][o];
      float w2 = s_wt[c4 * 4 + 2][o];
      float w3 = s_wt[c4 * 4 + 3][o];
#pragma unroll
      for (int j = 0; j < 32; j++) {
        float4 h = *(const float4*)(&s_h[sq * 32 + j][c4 * 4]);  // broadcast
        acc[j] = fmaf(h.x, w0, acc[j]);
        acc[j] = fmaf(h.y, w1, acc[j]);
        acc[j] = fmaf(h.z, w2, acc[j]);
        acc[j] = fmaf(h.w, w3, acc[j]);
      }
    }
    __syncthreads();
  }
  float m = -1e30f;
#pragma unroll
  for (int j = 0; j < 32; j++) m = fmaxf(m, acc[j]);
  s_red[sq][o] = m;
  __syncthreads();
  if (sq == 0) {
    m = fmaxf(fmaxf(s_red[0][o], s_red[1][o]), fmaxf(s_red[2][o], s_red[3][o]));
    out[(size_t)b * 1024 + ot * 64 + o] = fmaxf(m, 0.f);
  }
}

extern "C" void kernel_launch(void* const* d_in, const int* in_sizes, int n_in,
                              void* d_out, int out_size, void* d_ws, size_t ws_size,
                              hipStream_t stream) {
  const float* x = (const float*)d_in[0];
  const float* W1a = (const float*)d_in[1];
  const float* b1a = (const float*)d_in[2];
  const float* W1b = (const float*)d_in[3];
  const float* b1b = (const float*)d_in[4];
  const float* W2a = (const float*)d_in[5];
  const float* b2a = (const float*)d_in[6];
  const float* W2b = (const float*)d_in[7];
  const float* b2b = (const float*)d_in[8];
  const float* W3a = (const float*)d_in[9];
  const float* b3a = (const float*)d_in[10];
  const float* W3b = (const float*)d_in[11];
  const float* b3b = (const float*)d_in[12];
  float* out = (float*)d_out;

  // workspace carve (floats/ints; all segments 16B-aligned) — ~13.3 MB total
  float* nx1 = (float*)d_ws;                       // [16,512,3]
  int* idx1 = (int*)(nx1 + 16 * 512 * 3);          // [16,512,64]
  float* feat1 = (float*)(idx1 + 16 * 512 * 64);   // [16,512,128]
  float* nx2 = feat1 + 16 * 512 * 128;             // [16,128,3]
  int* idx2 = (int*)(nx2 + 16 * 128 * 3);          // [16,128,64]
  float* in3 = (float*)(idx2 + 16 * 128 * 64);     // [16,128,259] = [xyz2|feat2]
  float* h3 = in3 + 16 * 128 * 259;                // [16,128,512]

  fps1_kernel<<<B, 1024, 0, stream>>>(x, nx1, nullptr, 0, N, S1);
  ballq_kernel<<<(B * S1) / 4, 256, 0, stream>>>(x, nx1, idx1, N, S1, B * S1, 0.04f);
  sa1_kernel<<<B * S1, 256, 0, stream>>>(x, idx1, nx1, W1a, b1a, W1b, b1b, feat1);
  fps2_kernel<<<B, 512, 0, stream>>>(nx1, nx2, in3, 259, S1, S2);
  ballq_kernel<<<(B * S2) / 4, 256, 0, stream>>>(nx1, nx2, idx2, S1, S2, B * S2, 0.16f);
  sa2_kernel<<<B * S2, 256, 0, stream>>>(nx1, feat1, idx2, nx2, W2a, b2a, W2b, b2b, in3);
  mlp3a_kernel<<<256, 256, 0, stream>>>(in3, W3a, b3a, h3);
  mlp3b_kernel<<<256, 256, 0, stream>>>(h3, W3b, b3b, out);
}

// Round 4
// 1488.183 us; speedup vs baseline: 1.0383x; 1.0383x over previous
//
#include <hip/hip_runtime.h>

#define B 16
#define N 8192
#define S1 512
#define S2 128
#define K 64

// ---------------------------------------------------------------------------
// DPP helper: cross-lane reduction on the VALU (no LDS pipe).
// ---------------------------------------------------------------------------
template<int CTRL>
__device__ __forceinline__ unsigned dpp_u32(unsigned v) {
  return (unsigned)__builtin_amdgcn_update_dpp((int)v, (int)v, CTRL, 0xF, 0xF, false);
}

// u64 max reduction step: 2 DPP movs + u64 compare + 2 cndmask.
template<int CTRL>
__device__ __forceinline__ void red64(unsigned long long& k) {
  unsigned hi = (unsigned)(k >> 32), lo = (unsigned)k;
  unsigned ohi = dpp_u32<CTRL>(hi);
  unsigned olo = dpp_u32<CTRL>(lo);
  unsigned long long o = ((unsigned long long)ohi << 32) | olo;
  if (o > k) k = o;
}

// ---------------------------------------------------------------------------
// Farthest point sampling. ROUND-11 (R10 post-mortem): packed v2f math was
// the regression (VALUBusy 6.26->4.64%): CDNA4's SIMD-32 datapath gives
// v_pk_*_f32 NO throughput gain (2x datapath per op), while .x/.y winner
// extraction added dependent cndmask stalls. The waves_per_eu(max) pin DID
// work (state resident at VGPR 52). This round runs the never-tested combo:
//  * scalar math (exact R9 inner loop, bit-identical semantics)
//  * resident state via waves_per_eu(4,4) on the 1024-thr wrapper
//    (removes R9's ~120 instr/iter of forced reloads + address recompute)
//  * winner-coord fetch from an LDS copy of all points (s_pts, 96KB for
//    fps1; one block/CU so the footprint is free): uniform ds_read
//    broadcast ~120cyc vs ~300cyc L2 round-trip on the serial tail.
// Tie semantics (= jnp.argmax first occurrence = min idx): in-thread strict
// > over ascending i (p = t + i*NT is ascending per thread); cross-lane/wave
// via u64 key (dist_bits<<32)|~idx, max ~idx == min idx. Stage-2: lane63 ds
// atomicMax(u64) on one LDS cell; 3-cell rotation cleared one iter ahead is
// race-free with a single barrier per iteration.
// Requires n == PT * NT exactly; npoint <= MAXP; n <= MAXN.
// ---------------------------------------------------------------------------
template<int NT, int PT, int MAXP, int MAXN>
__device__ __forceinline__ void fps_body(
    const float* __restrict__ pts, float* __restrict__ out_xyz,
    float* __restrict__ out2, int out2_stride, int n, int npoint) {
  const int b = blockIdx.x;
  const int t = threadIdx.x;
  const int lane = t & 63;
  const float* base = pts + (size_t)b * n * 3;
  __shared__ unsigned long long cell[3];
  __shared__ float s_out[MAXP * 3];
  __shared__ float s_pts[MAXN * 3];  // coord cache for the winner fetch
  if (t == 0) { cell[0] = 0ull; cell[1] = 0ull; cell[2] = 0ull; }
  float px[PT], py[PT], pz[PT], mind[PT];
#pragma unroll
  for (int i = 0; i < PT; i++) {
    int p = t + i * NT;
    px[i] = base[p * 3 + 0];
    py[i] = base[p * 3 + 1];
    pz[i] = base[p * 3 + 2];
    mind[i] = 1e10f;  // matches reference init 1e10
    s_pts[p * 3 + 0] = px[i];
    s_pts[p * 3 + 1] = py[i];
    s_pts[p * 3 + 2] = pz[i];
  }
  // first sample is index 0
  float cx = base[0], cy = base[1], cz = base[2];
  __syncthreads();
  for (int it = 0; it < npoint; it++) {
    if (t == 0) {
      s_out[it * 3 + 0] = cx; s_out[it * 3 + 1] = cy; s_out[it * 3 + 2] = cz;
    }
    float bv = -1.0f;
    int bc = 0;
#pragma unroll
    for (int i = 0; i < PT; i++) {
      float dx = px[i] - cx, dy = py[i] - cy, dz = pz[i] - cz;
      float d = dx * dx;
      d = fmaf(dy, dy, d);
      d = fmaf(dz, dz, d);
      float md = fminf(mind[i], d);
      mind[i] = md;
      if (md > bv) { bv = md; bc = i; }
    }
    unsigned long long k =
        ((unsigned long long)__float_as_uint(bv) << 32) | (~(unsigned)(t + bc * NT));
    red64<0x111>(k);  // row_shr:1
    red64<0x112>(k);  // row_shr:2
    red64<0x114>(k);  // row_shr:4
    red64<0x118>(k);  // row_shr:8
    red64<0x142>(k);  // row_bcast:15
    red64<0x143>(k);  // row_bcast:31  -> lane 63 has wave winner
    if (lane == 63) atomicMax(&cell[it % 3], k);
    if (t == 0) cell[(it + 1) % 3] = 0ull;  // prep next iter's cell (race-free, see header)
    __syncthreads();
    unsigned long long wk = cell[it % 3];
    int ui = __builtin_amdgcn_readfirstlane((int)(~(unsigned)wk));
    const float* q = s_pts + ui * 3;  // uniform LDS broadcast, conflict-free
    cx = q[0]; cy = q[1]; cz = q[2];
  }
  // epilogue: flush staged sample coords to global (coalesced)
  for (int e = t; e < npoint * 3; e += NT)
    out_xyz[(size_t)b * npoint * 3 + e] = s_out[e];
  if (out2) {
    for (int e = t; e < npoint; e += NT) {
      float* o2 = out2 + ((size_t)b * npoint + e) * out2_stride;
      o2[0] = s_out[e * 3 + 0];
      o2[1] = s_out[e * 3 + 1];
      o2[2] = s_out[e * 3 + 2];
    }
  }
}

// Wrappers pin the VGPR budget to the real occupancy (one block/CU):
// fps1: 1024 thr = 4 waves/SIMD -> waves_per_eu(4,4) -> 128-VGPR budget;
//       state is 32 floats + ~30 overhead, fits resident.
// fps2: 512 thr = 2 waves/SIMD -> waves_per_eu(2,2) -> 256-VGPR budget.
__global__ __launch_bounds__(1024) __attribute__((amdgpu_waves_per_eu(4, 4)))
void fps1_kernel(const float* __restrict__ pts, float* __restrict__ out_xyz,
                 float* __restrict__ out2, int out2_stride, int n, int npoint) {
  fps_body<1024, 8, 512, 8192>(pts, out_xyz, out2, out2_stride, n, npoint);
}

__global__ __launch_bounds__(512) __attribute__((amdgpu_waves_per_eu(2, 2)))
void fps2_kernel(const float* __restrict__ pts, float* __restrict__ out_xyz,
                 float* __restrict__ out2, int out2_stride, int n, int npoint) {
  fps_body<512, 1, 128, 512>(pts, out_xyz, out2, out2_stride, n, npoint);
}

// ---------------------------------------------------------------------------
// Ball query: one wave per center; ballot-scan points in index order, emit
// first K in-radius indices; fill tail with first hit (or n-1 if none).
// ---------------------------------------------------------------------------
__global__ __launch_bounds__(256) void ballq_kernel(
    const float* __restrict__ pts, const float* __restrict__ ctr,
    int* __restrict__ idx, int n, int ns, int total, float r2) {
  int gid = blockIdx.x * blockDim.x + threadIdx.x;
  int wid = gid >> 6;
  int lane = threadIdx.x & 63;
  if (wid >= total) return;
  int b = wid / ns, s = wid - b * ns;
  const float* pb = pts + (size_t)b * n * 3;
  const float* c = ctr + ((size_t)b * ns + s) * 3;
  float cx = c[0], cy = c[1], cz = c[2];
  float sc = cx * cx + cy * cy + cz * cz;
  int* out = idx + ((size_t)b * ns + s) * K;
  int cnt = 0, first = n - 1;
  for (int base = 0; base < n && cnt < K; base += 64) {
    int p = base + lane;
    float x = pb[p * 3 + 0], y = pb[p * 3 + 1], z = pb[p * 3 + 2];
    float sp = x * x + y * y + z * z;
    float dot = cx * x + cy * y + cz * z;
    float d2 = sc + sp - 2.0f * dot;
    bool inr = d2 < r2;
    unsigned long long m = __ballot(inr);
    if (cnt == 0 && m != 0ull) first = base + __ffsll((long long)m) - 1;
    int pre = (int)__popcll(m & ((1ull << lane) - 1ull));
    if (inr && (cnt + pre) < K) out[cnt + pre] = p;
    cnt += (int)__popcll(m);
  }
  if (cnt > K) cnt = K;
  if (lane >= cnt) out[lane] = first;
}

// ---------------------------------------------------------------------------
// SA1 grouped MLP: per group (b,s): gather 64 local coords, h = relu(W1a*g+b),
// out[o] = relu(max_k (W1b[o].h[k] + b)). h staged in LDS; W1b row in regs;
// all LDS reads are wave-uniform broadcasts (conflict-free).
// ---------------------------------------------------------------------------
__global__ __launch_bounds__(256) void sa1_kernel(
    const float* __restrict__ xyz, const int* __restrict__ idx,
    const float* __restrict__ ctr, const float* __restrict__ W1a,
    const float* __restrict__ b1a, const float* __restrict__ W1b,
    const float* __restrict__ b1b, float* __restrict__ feat) {
  __shared__ float s_l[K][3];
  __shared__ float s_h[K][64];
  __shared__ float s_red[128];
  int blk = blockIdx.x;
  int b = blk >> 9, s = blk & 511;
  int tid = threadIdx.x;
  const int* gi = idx + ((size_t)b * S1 + s) * K;
  const float* c = ctr + ((size_t)b * S1 + s) * 3;
  float cx = c[0], cy = c[1], cz = c[2];
  if (tid < K) {
    int p = gi[tid];
    const float* q = xyz + ((size_t)b * N + p) * 3;
    s_l[tid][0] = q[0] - cx;
    s_l[tid][1] = q[1] - cy;
    s_l[tid][2] = q[2] - cz;
  }
  __syncthreads();
  for (int e = tid; e < K * 64; e += 256) {
    int k = e >> 6, o = e & 63;
    float v = b1a[o] + W1a[o * 3 + 0] * s_l[k][0] + W1a[o * 3 + 1] * s_l[k][1] +
              W1a[o * 3 + 2] * s_l[k][2];
    s_h[k][o] = fmaxf(v, 0.f);
  }
  __syncthreads();
  int o = tid & 127, half = tid >> 7;
  float w[64];
  const float4* wp = (const float4*)(W1b + o * 64);  // 256B-aligned rows
#pragma unroll
  for (int c4 = 0; c4 < 16; c4++) {
    float4 t4 = wp[c4];
    w[c4 * 4 + 0] = t4.x; w[c4 * 4 + 1] = t4.y;
    w[c4 * 4 + 2] = t4.z; w[c4 * 4 + 3] = t4.w;
  }
  float bias = b1b[o];
  float m = -1e30f;
  int k0 = half * 32;
  for (int k = k0; k < k0 + 32; k++) {
    float acc = bias;
    const float4* hp = (const float4*)(&s_h[k][0]);
#pragma unroll
    for (int c4 = 0; c4 < 16; c4++) {
      float4 h = hp[c4];  // broadcast across the wave
      acc = fmaf(h.x, w[c4 * 4 + 0], acc);
      acc = fmaf(h.y, w[c4 * 4 + 1], acc);
      acc = fmaf(h.z, w[c4 * 4 + 2], acc);
      acc = fmaf(h.w, w[c4 * 4 + 3], acc);
    }
    m = fmaxf(m, acc);
  }
  if (half == 1) s_red[o] = m;
  __syncthreads();
  if (half == 0) {
    m = fmaxf(m, s_red[o]);
    feat[((size_t)b * S1 + s) * 128 + o] = fmaxf(m, 0.f);  // relu(max) == max(relu)
  }
}

// ---------------------------------------------------------------------------
// SA2 grouped MLP: group input = [local xyz (3) | gathered feat1 (128)] = 131,
// 131 -> 128 (relu) -> 256 (relu) -> max over 64 samples. Output written
// directly into the concat buffer in3[b][s][3..258]; in3[..][0..2] = xyz2
// (written by fps2_kernel's out2 path).
// ---------------------------------------------------------------------------
__global__ __launch_bounds__(256) void sa2_kernel(
    const float* __restrict__ xyz1, const float* __restrict__ feat1,
    const int* __restrict__ idx, const float* __restrict__ ctr,
    const float* __restrict__ W2a, const float* __restrict__ b2a,
    const float* __restrict__ W2b, const float* __restrict__ b2b,
    float* __restrict__ in3) {
  __shared__ int s_pi[K];
  __shared__ float s_g[K][132];  // 131 cols + pad; row = 528B (16B aligned)
  __shared__ float s_h[K][128];
  int blk = blockIdx.x;
  int b = blk >> 7, s = blk & 127;
  int tid = threadIdx.x;
  const int* gi = idx + ((size_t)b * S2 + s) * K;
  const float* c = ctr + ((size_t)b * S2 + s) * 3;
  float cx = c[0], cy = c[1], cz = c[2];
  if (tid < K) {
    int p = gi[tid];
    s_pi[tid] = p;
    const float* q = xyz1 + ((size_t)b * S1 + p) * 3;
    s_g[tid][0] = q[0] - cx;
    s_g[tid][1] = q[1] - cy;
    s_g[tid][2] = q[2] - cz;
  }
  __syncthreads();
  for (int e = tid; e < K * 128; e += 256) {
    int k = e >> 7, f = e & 127;
    s_g[k][3 + f] = feat1[((size_t)b * S1 + s_pi[k]) * 128 + f];
  }
  __syncthreads();
  // phase A: s_h[k][o] = relu(W2a[o] . g[k] + b2a[o]), o in [0,128), k split in halves
  {
    int o = tid & 127, half = tid >> 7, k0 = half * 32;
    const float* wr = W2a + o * 131;
    float acc[32];
    float bias = b2a[o];
#pragma unroll
    for (int j = 0; j < 32; j++) acc[j] = bias;
    for (int c4 = 0; c4 < 32; c4++) {
      float w0 = wr[c4 * 4 + 0], w1 = wr[c4 * 4 + 1];
      float w2 = wr[c4 * 4 + 2], w3 = wr[c4 * 4 + 3];
#pragma unroll
      for (int j = 0; j < 32; j++) {
        float4 g = *(const float4*)(&s_g[k0 + j][c4 * 4]);
        acc[j] = fmaf(g.x, w0, acc[j]);
        acc[j] = fmaf(g.y, w1, acc[j]);
        acc[j] = fmaf(g.z, w2, acc[j]);
        acc[j] = fmaf(g.w, w3, acc[j]);
      }
    }
    float w0 = wr[128], w1 = wr[129], w2 = wr[130];
#pragma unroll
    for (int j = 0; j < 32; j++) {
      acc[j] = fmaf(s_g[k0 + j][128], w0, acc[j]);
      acc[j] = fmaf(s_g[k0 + j][129], w1, acc[j]);
      acc[j] = fmaf(s_g[k0 + j][130], w2, acc[j]);
      s_h[k0 + j][o] = fmaxf(acc[j], 0.f);
    }
  }
  __syncthreads();
  // phase B: out[o] = relu(max_k (W2b[o] . h[k] + b2b[o])), o = tid in [0,256)
  {
    int o = tid;
    const float4* wp = (const float4*)(W2b + o * 128);  // 512B-aligned rows
    float bias = b2b[o];
    float acc[K];
#pragma unroll
    for (int k = 0; k < K; k++) acc[k] = bias;
    for (int c4 = 0; c4 < 32; c4++) {
      float4 w4 = wp[c4];
#pragma unroll
      for (int k = 0; k < K; k++) {
        float4 h = *(const float4*)(&s_h[k][c4 * 4]);  // broadcast
        acc[k] = fmaf(h.x, w4.x, acc[k]);
        acc[k] = fmaf(h.y, w4.y, acc[k]);
        acc[k] = fmaf(h.z, w4.z, acc[k]);
        acc[k] = fmaf(h.w, w4.w, acc[k]);
      }
    }
    float m = -1e30f;
#pragma unroll
    for (int k = 0; k < K; k++) m = fmaxf(m, acc[k]);
    in3[((size_t)b * S2 + s) * 259 + 3 + o] = fmaxf(m, 0.f);
  }
}

// ---------------------------------------------------------------------------
// Final MLP layer a: h3[b][s][o] = relu(W3a[o] . in3[b][s] + b3a[o]).
// ---------------------------------------------------------------------------
__global__ __launch_bounds__(256) void mlp3a_kernel(
    const float* __restrict__ in3, const float* __restrict__ W3a,
    const float* __restrict__ b3a, float* __restrict__ h3) {
  __shared__ float s_wt[64][65];
  __shared__ float s_a[64][64];
  int blk = blockIdx.x;
  int b = blk >> 4, r = blk & 15;
  int ot = r >> 1, sh = r & 1;
  int tid = threadIdx.x;
  int o = tid & 63, sq = tid >> 6;
  float acc[16];
  float bias = b3a[ot * 64 + o];
#pragma unroll
  for (int j = 0; j < 16; j++) acc[j] = bias;
  for (int ch = 0; ch < 5; ch++) {
    int cb = ch * 64;
    int len = (ch == 4) ? 3 : 64;
    for (int e = tid; e < 4096; e += 256) {
      int oo = e >> 6, cc = e & 63;
      if (cc < len) s_wt[cc][oo] = W3a[(size_t)(ot * 64 + oo) * 259 + cb + cc];
    }
    for (int e = tid; e < 4096; e += 256) {
      int ss = e >> 6, cc = e & 63;
      if (cc < len) s_a[ss][cc] = in3[((size_t)b * S2 + sh * 64 + ss) * 259 + cb + cc];
    }
    __syncthreads();
    for (int cc = 0; cc < len; cc++) {
      float wv = s_wt[cc][o];
#pragma unroll
      for (int j = 0; j < 16; j++)
        acc[j] = fmaf(wv, s_a[sq * 16 + j][cc], acc[j]);
    }
    __syncthreads();
  }
#pragma unroll
  for (int j = 0; j < 16; j++) {
    int s = sh * 64 + sq * 16 + j;
    h3[((size_t)b * S2 + s) * 512 + ot * 64 + o] = fmaxf(acc[j], 0.f);
  }
}

// ---------------------------------------------------------------------------
// Final MLP layer b + global max-pool over the 128 proposals:
// out[b][o] = relu(max_s (W3b[o] . h3[b][s] + b3b[o])).
// ---------------------------------------------------------------------------
__global__ __launch_bounds__(256) void mlp3b_kernel(
    const float* __restrict__ h3, const float* __restrict__ W3b,
    const float* __restrict__ b3b, float* __restrict__ out) {
  __shared__ float s_wt[64][65];
  __shared__ float s_h[128][64];
  __shared__ float s_red[4][64];
  int blk = blockIdx.x;
  int b = blk >> 4, ot = blk & 15;
  int tid = threadIdx.x;
  int o = tid & 63, sq = tid >> 6;
  float acc[32];
  float bias = b3b[ot * 64 + o];
#pragma unroll
  for (int j = 0; j < 32; j++) acc[j] = bias;
  for (int ch = 0; ch < 8; ch++) {
    int cb = ch * 64;
    for (int e = tid; e < 4096; e += 256) {
      int oo = e >> 6, cc = e & 63;
      s_wt[cc][oo] = W3b[(size_t)(ot * 64 + oo) * 512 + cb + cc];
    }
    for (int e = tid; e < 8192; e += 256) {
      int ss = e >> 6, cc = e & 63;
      s_h[ss][cc] = h3[((size_t)b * S2 + ss) * 512 + cb + cc];
    }
    __syncthreads();
    for (int c4 = 0; c4 < 16; c4++) {
      float w0 = s_wt[c4 * 4 + 0][o];
      float w1 = s_wt[c4 * 4 + 1][o];
      float w2 = s_wt[c4 * 4 + 2][o];
      float w3 = s_wt[c4 * 4 + 3][o];
#pragma unroll
      for (int j = 0; j < 32; j++) {
        float4 h = *(const float4*)(&s_h[sq * 32 + j][c4 * 4]);  // broadcast
        acc[j] = fmaf(h.x, w0, acc[j]);
        acc[j] = fmaf(h.y, w1, acc[j]);
        acc[j] = fmaf(h.z, w2, acc[j]);
        acc[j] = fmaf(h.w, w3, acc[j]);
      }
    }
    __syncthreads();
  }
  float m = -1e30f;
#pragma unroll
  for (int j = 0; j < 32; j++) m = fmaxf(m, acc[j]);
  s_red[sq][o] = m;
  __syncthreads();
  if (sq == 0) {
    m = fmaxf(fmaxf(s_red[0][o], s_red[1][o]), fmaxf(s_red[2][o], s_red[3][o]));
    out[(size_t)b * 1024 + ot * 64 + o] = fmaxf(m, 0.f);
  }
}

extern "C" void kernel_launch(void* const* d_in, const int* in_sizes, int n_in,
                              void* d_out, int out_size, void* d_ws, size_t ws_size,
                              hipStream_t stream) {
  const float* x = (const float*)d_in[0];
  const float* W1a = (const float*)d_in[1];
  const float* b1a = (const float*)d_in[2];
  const float* W1b = (const float*)d_in[3];
  const float* b1b = (const float*)d_in[4];
  const float* W2a = (const float*)d_in[5];
  const float* b2a = (const float*)d_in[6];
  const float* W2b = (const float*)d_in[7];
  const float* b2b = (const float*)d_in[8];
  const float* W3a = (const float*)d_in[9];
  const float* b3a = (const float*)d_in[10];
  const float* W3b = (const float*)d_in[11];
  const float* b3b = (const float*)d_in[12];
  float* out = (float*)d_out;

  // workspace carve (floats/ints; all segments 16B-aligned) — ~13.3 MB total
  float* nx1 = (float*)d_ws;                       // [16,512,3]
  int* idx1 = (int*)(nx1 + 16 * 512 * 3);          // [16,512,64]
  float* feat1 = (float*)(idx1 + 16 * 512 * 64);   // [16,512,128]
  float* nx2 = feat1 + 16 * 512 * 128;             // [16,128,3]
  int* idx2 = (int*)(nx2 + 16 * 128 * 3);          // [16,128,64]
  float* in3 = (float*)(idx2 + 16 * 128 * 64);     // [16,128,259] = [xyz2|feat2]
  float* h3 = in3 + 16 * 128 * 259;                // [16,128,512]

  fps1_kernel<<<B, 1024, 0, stream>>>(x, nx1, nullptr, 0, N, S1);
  ballq_kernel<<<(B * S1) / 4, 256, 0, stream>>>(x, nx1, idx1, N, S1, B * S1, 0.04f);
  sa1_kernel<<<B * S1, 256, 0, stream>>>(x, idx1, nx1, W1a, b1a, W1b, b1b, feat1);
  fps2_kernel<<<B, 512, 0, stream>>>(nx1, nx2, in3, 259, S1, S2);
  ballq_kernel<<<(B * S2) / 4, 256, 0, stream>>>(nx1, nx2, idx2, S1, S2, B * S2, 0.16f);
  sa2_kernel<<<B * S2, 256, 0, stream>>>(nx1, feat1, idx2, nx2, W2a, b2a, W2b, b2b, in3);
  mlp3a_kernel<<<256, 256, 0, stream>>>(in3, W3a, b3a, h3);
  mlp3b_kernel<<<256, 256, 0, stream>>>(h3, W3b, b3b, out);
}